// Round 11
// baseline (202.351 us; speedup 1.0000x reference)
//
#include <hip/hip_runtime.h>
#include <hip/hip_bf16.h>
#include <math.h>

// Problem constants
#define BB 4
#define SS 2048
#define DD 512
#define HH 8
#define DHH 64
#define DFF 2048
#define MM (BB*SS)          // 8192 rows
#define QKV_N (3*DD)        // 1536

typedef float  f32x4  __attribute__((ext_vector_type(4)));
typedef __bf16 bf16x8 __attribute__((ext_vector_type(8)));
typedef unsigned short us8 __attribute__((ext_vector_type(8)));
typedef unsigned short us4 __attribute__((ext_vector_type(4)));

// ---- bf16 helpers (RNE, finite inputs) ----
__device__ __forceinline__ unsigned short f2bf(float v) {
    unsigned int u = __float_as_uint(v);
    unsigned int r = (u + 0x7fffu + ((u >> 16) & 1u)) >> 16;
    return (unsigned short)r;
}
__device__ __forceinline__ float bf2f(unsigned short h) {
    return __uint_as_float(((unsigned int)h) << 16);
}

__device__ __forceinline__ f32x4 mfma_bf16(us8 a, us8 b, f32x4 c) {
    return __builtin_amdgcn_mfma_f32_16x16x32_bf16(
        __builtin_bit_cast(bf16x8, a), __builtin_bit_cast(bf16x8, b), c, 0, 0, 0);
}

// NOTE: the imm offset arg of global_load_lds applies to BOTH global and LDS
// addresses (round-9 NaN post-mortem) — always pass 0 and bump pointers instead.
__device__ __forceinline__ void gload_lds16(const void* gsrc, void* ldst) {
    __builtin_amdgcn_global_load_lds(
        (const __attribute__((address_space(1))) void*)gsrc,
        (__attribute__((address_space(3))) void*)ldst, 16, 0, 0);
}

// Split-bf16 global layout: per row of K elements -> K/32 blocks of 128B:
// [32 x bf16 hi][32 x bf16 lo]. ushort index: row*2K + (k/32)*64 + (k%32); lo at +32.

// ---------------------------------------------------------------- LayerNorm -> split bf16
__global__ __launch_bounds__(128)
void ln_kernel(const float* __restrict__ x, const float* __restrict__ g,
               const float* __restrict__ beta, unsigned short* __restrict__ outp)
{
    const int row = blockIdx.x;
    const int t = threadIdx.x;               // 128 threads, 4 floats each
    const float4 v = reinterpret_cast<const float4*>(x + (size_t)row * DD)[t];

    float s  = v.x + v.y + v.z + v.w;
    float s2 = v.x*v.x + v.y*v.y + v.z*v.z + v.w*v.w;
    #pragma unroll
    for (int off = 32; off >= 1; off >>= 1) {
        s  += __shfl_xor(s,  off);
        s2 += __shfl_xor(s2, off);
    }
    __shared__ float red[2][2];
    const int lane = t & 63, wid = t >> 6;
    if (lane == 0) { red[wid][0] = s; red[wid][1] = s2; }
    __syncthreads();
    const float ts  = red[0][0] + red[1][0];
    const float ts2 = red[0][1] + red[1][1];
    const float mu  = ts * (1.0f / DD);
    const float var = ts2 * (1.0f / DD) - mu * mu;
    const float rs  = rsqrtf(var + 1e-5f);

    const float4 gv = reinterpret_cast<const float4*>(g)[t];
    const float4 bv = reinterpret_cast<const float4*>(beta)[t];
    float vals[4];
    vals[0] = (v.x - mu) * rs * gv.x + bv.x;
    vals[1] = (v.y - mu) * rs * gv.y + bv.y;
    vals[2] = (v.z - mu) * rs * gv.z + bv.z;
    vals[3] = (v.w - mu) * rs * gv.w + bv.w;

    us4 hv, lv;
    #pragma unroll
    for (int i = 0; i < 4; ++i) {
        hv[i] = f2bf(vals[i]);
        lv[i] = f2bf(vals[i] - bf2f(hv[i]));
    }
    const int k = t * 4;
    size_t o = (size_t)row * 1024 + (size_t)(k >> 5) * 64 + (k & 31);
    *reinterpret_cast<us4*>(outp + o)      = hv;
    *reinterpret_cast<us4*>(outp + o + 32) = lv;
}

// ---------------------------------------------------------------- fp32 -> split bf16 (all weights, one launch)
// units 0..262143: w_in|w_out|w_ff1 as 4096 rows x 512 K -> dst3
// units 262144..393215: w_ff2 512 rows x 2048 K -> dstw2
__global__ __launch_bounds__(256)
void conv_all(const float* __restrict__ w_in, const float* __restrict__ w_out,
              const float* __restrict__ w_ff1, const float* __restrict__ w_ff2,
              unsigned short* __restrict__ dst3, unsigned short* __restrict__ dstw2)
{
    const int gid = blockIdx.x * 256 + threadIdx.x;
    const float* src;
    unsigned short* dst;
    size_t o;
    if (gid < 262144) {
        const int r  = gid >> 6;
        const int k0 = (gid & 63) * 8;
        src = (r < 1536) ? w_in  + (size_t)r * 512 + k0
            : (r < 2048) ? w_out + (size_t)(r - 1536) * 512 + k0
                         : w_ff1 + (size_t)(r - 2048) * 512 + k0;
        o = (size_t)r * 1024 + (size_t)(k0 >> 5) * 64 + (k0 & 31);
        dst = dst3;
    } else {
        const int g  = gid - 262144;
        const int r  = g >> 8;
        const int k0 = (g & 255) * 8;
        src = w_ff2 + (size_t)r * 2048 + k0;
        o = (size_t)r * 4096 + (size_t)(k0 >> 5) * 64 + (k0 & 31);
        dst = dstw2;
    }
    us8 h, l;
    #pragma unroll
    for (int i = 0; i < 8; ++i) {
        float v = src[i];
        h[i] = f2bf(v);
        l[i] = f2bf(v - bf2f(h[i]));
    }
    *reinterpret_cast<us8*>(dst + o)      = h;
    *reinterpret_cast<us8*>(dst + o + 32) = l;
}

// ---------------------------------------------------------------- split-bf16 MFMA GEMM
// BM=128, BN=64: 48KB LDS -> 3 blocks/CU (12 waves) — measured-best regime.
// 2-barrier double-buffered loop, unrolled x2 with STATIC buffer indices
// (ds_read offset-imm addressing). Staging pointers advance +1 K-tile (128B)
// right after each STAGE; gload imm offset is always 0 (see NOTE above).
// XCD-aware bijective block swizzle (requires nwg % 8 == 0).
// EPI: 0 = bias -> fp32 Cf; 1 = bias + Res -> fp32 Cf; 2 = bias + GELU -> split Cs
template<int BN, int EPI>
__global__ __launch_bounds__(256, 3)
void gemm_tile(const unsigned short* __restrict__ Ax, const unsigned short* __restrict__ Wx,
               const float* __restrict__ bias, const float* __restrict__ Res,
               float* __restrict__ Cf, unsigned short* __restrict__ Cs,
               int N, int K)
{
    constexpr int NF   = BN / 32;          // n-frags per wave
    constexpr int NB   = BN / 32;          // B stage loads per thread
    constexpr int AUSH = 128 * 64;         // ushorts per A buffer
    constexpr int BUSH = BN * 64;
    __shared__ unsigned short smem[2][AUSH + BUSH];

    const int tid  = threadIdx.x;
    const int wave = tid >> 6, lane = tid & 63;
    const int wm = wave >> 1, wn = wave & 1;
    const int lr = lane & 15, kc = lane >> 4;

    // XCD swizzle: contiguous chunks of the flat grid per XCD
    const int nwg = gridDim.x * gridDim.y;
    int bid = blockIdx.y * gridDim.x + blockIdx.x;
    bid = (bid & 7) * (nwg >> 3) + (bid >> 3);
    const int bn = (bid % gridDim.x) * BN;
    const int bm = (bid / gridDim.x) * 128;

    const int K2  = K * 2;
    const int nkb = K >> 5;                // even for all call sites (16 or 64)

    // LDS ushort offsets of hi fragments (lo = ^32); chunk swizzled by row&7
    int aoff[4], woff[NF];
    #pragma unroll
    for (int m = 0; m < 4; ++m) {
        const int ra = wm * 64 + m * 16 + lr;
        aoff[m] = ra * 64 + ((kc ^ (ra & 7)) * 8);
    }
    #pragma unroll
    for (int n = 0; n < NF; ++n) {
        const int rw = wn * (NF * 16) + n * 16 + lr;
        woff[n] = AUSH + rw * 64 + ((kc ^ (rw & 7)) * 8);
    }

    f32x4 acc[4][NF];
    #pragma unroll
    for (int i = 0; i < 4; ++i)
        #pragma unroll
        for (int j = 0; j < NF; ++j) acc[i][j] = (f32x4){0.f, 0.f, 0.f, 0.f};

    // persistent staging pointers; source chunk = LDS slot ^ (row&7)
    const unsigned short* aP[4];
    const unsigned short* wP[NB];
    #pragma unroll
    for (int j = 0; j < 4; ++j) {
        const int off = j * 2048 + tid * 8;
        const int row = off >> 6;
        const int q   = ((off >> 3) & 7) ^ (row & 7);
        aP[j] = Ax + (size_t)(bm + row) * K2 + q * 8;
    }
    #pragma unroll
    for (int j = 0; j < NB; ++j) {
        const int off = j * 2048 + tid * 8;
        const int row = off >> 6;
        const int q   = ((off >> 3) & 7) ^ (row & 7);
        wP[j] = Wx + (size_t)(bn + row) * K2 + q * 8;
    }

// stage the K-tile at current pointer position into buffer BUF, then advance
#define STAGE(BUF) do {                                                        \
        _Pragma("unroll")                                                      \
        for (int j = 0; j < 4; ++j)                                            \
            gload_lds16(aP[j], &smem[BUF][j * 2048 + tid * 8]);                \
        _Pragma("unroll")                                                      \
        for (int j = 0; j < NB; ++j)                                           \
            gload_lds16(wP[j], &smem[BUF][AUSH + j * 2048 + tid * 8]);         \
    } while (0)

#define ADV() do {                                                             \
        _Pragma("unroll")                                                      \
        for (int j = 0; j < 4; ++j) aP[j] += 64;                               \
        _Pragma("unroll")                                                      \
        for (int j = 0; j < NB; ++j) wP[j] += 64;                              \
    } while (0)

// compute one K-tile from buffer BUF (static index -> offset-imm ds_reads)
#define COMPUTE(BUF) do {                                                      \
        const unsigned short* S = smem[BUF];                                   \
        us8 ah[4], al[4], wh[NF], wl[NF];                                      \
        _Pragma("unroll")                                                      \
        for (int m = 0; m < 4; ++m) {                                          \
            ah[m] = *reinterpret_cast<const us8*>(S + aoff[m]);                \
            al[m] = *reinterpret_cast<const us8*>(S + (aoff[m] ^ 32));         \
        }                                                                      \
        _Pragma("unroll")                                                      \
        for (int n = 0; n < NF; ++n) {                                         \
            wh[n] = *reinterpret_cast<const us8*>(S + woff[n]);                \
            wl[n] = *reinterpret_cast<const us8*>(S + (woff[n] ^ 32));         \
        }                                                                      \
        _Pragma("unroll")                                                      \
        for (int m = 0; m < 4; ++m)                                            \
            _Pragma("unroll")                                                  \
            for (int n = 0; n < NF; ++n) {                                     \
                acc[m][n] = mfma_bf16(ah[m], wh[n], acc[m][n]);                \
                acc[m][n] = mfma_bf16(ah[m], wl[n], acc[m][n]);                \
                acc[m][n] = mfma_bf16(al[m], wh[n], acc[m][n]);                \
            }                                                                  \
    } while (0)

    STAGE(0); ADV();                                // tile 0 -> buf0
    for (int kb = 0; kb < nkb; kb += 2) {
        __syncthreads();                            // buf0 arrived; prev buf1 readers done
        STAGE(1); ADV();                            // tile kb+1 -> buf1
        COMPUTE(0);                                 // tile kb
        __syncthreads();                            // buf1 arrived; buf0 readers done
        if (kb + 2 < nkb) STAGE(0);                 // tile kb+2 -> buf0
        ADV();
        COMPUTE(1);                                 // tile kb+1
    }
#undef STAGE
#undef ADV
#undef COMPUTE

    // epilogue; C/D layout: col = lane&15, row = (lane>>4)*4 + reg
    float bvn[NF];
    #pragma unroll
    for (int n = 0; n < NF; ++n) bvn[n] = bias[bn + wn * (NF * 16) + n * 16 + lr];

    #pragma unroll
    for (int m = 0; m < 4; ++m) {
        #pragma unroll
        for (int j = 0; j < 4; ++j) {
            const int row = bm + wm * 64 + m * 16 + kc * 4 + j;
            #pragma unroll
            for (int n = 0; n < NF; ++n) {
                const int col = bn + wn * (NF * 16) + n * 16 + lr;
                float v = acc[m][n][j] + bvn[n];
                if constexpr (EPI == 1) v += Res[(size_t)row * N + col];
                if constexpr (EPI == 2) {
                    v = 0.5f * v * (1.0f + erff(v * 0.70710678118654752f));
                    unsigned short h = f2bf(v);
                    unsigned short l = f2bf(v - bf2f(h));
                    size_t o = (size_t)row * (size_t)(N * 2) + (size_t)(col >> 5) * 64 + (col & 31);
                    Cs[o]      = h;
                    Cs[o + 32] = l;
                } else {
                    Cf[(size_t)row * N + col] = v;
                }
            }
        }
    }
}

// ---------------------------------------------------------------- Local attention (fp32 in, split out)
__global__ __launch_bounds__(256)
void attn_kernel(const float* __restrict__ qkv, unsigned short* __restrict__ ctx)
{
    constexpr int RAD = 4;
    constexpr int TQ  = 64;
    constexpr int KROWS = TQ + 2 * RAD;   // 72
    constexpr int LDK = DHH + 4;          // 68

    __shared__ float Ks[KROWS][LDK];
    __shared__ float Vs[KROWS][LDK];

    const int t  = threadIdx.x;
    const int qt = blockIdx.x;
    const int b  = blockIdx.y;
    const int h  = blockIdx.z;
    const int q0 = qt * TQ;
    const float* base = qkv + ((size_t)b * SS) * QKV_N + h * DHH;

    for (int idx = t; idx < KROWS * (DHH / 4); idx += 256) {
        const int row = idx >> 4;
        const int c4  = idx & 15;
        const int gr  = q0 - RAD + row;
        float4 kv = make_float4(0.f, 0.f, 0.f, 0.f);
        float4 vv = kv;
        if (gr >= 0 && gr < SS) {
            const float* p = base + (size_t)gr * QKV_N;
            kv = *reinterpret_cast<const float4*>(p + DD     + c4 * 4);
            vv = *reinterpret_cast<const float4*>(p + 2 * DD + c4 * 4);
        }
        *reinterpret_cast<float4*>(&Ks[row][c4 * 4]) = kv;
        *reinterpret_cast<float4*>(&Vs[row][c4 * 4]) = vv;
    }
    __syncthreads();

    const int qi   = t >> 2;
    const int quad = t & 3;
    const int gq   = q0 + qi;
    const int d0   = quad * 16;

    const float* qp = base + (size_t)gq * QKV_N + d0;
    float4 q[4];
    #pragma unroll
    for (int i = 0; i < 4; ++i) q[i] = *reinterpret_cast<const float4*>(qp + i * 4);

    float s[9];
    #pragma unroll
    for (int j = 0; j < 9; ++j) {
        const float* kr = &Ks[qi + j][d0];
        float p = 0.f;
        #pragma unroll
        for (int i = 0; i < 4; ++i) {
            const float4 k4 = *reinterpret_cast<const float4*>(kr + i * 4);
            p += q[i].x * k4.x + q[i].y * k4.y + q[i].z * k4.z + q[i].w * k4.w;
        }
        p += __shfl_xor(p, 1);
        p += __shfl_xor(p, 2);
        const int gk = gq + j - RAD;
        s[j] = (gk >= 0 && gk < SS) ? p * 0.125f : -INFINITY;
    }
    float mx = s[0];
    #pragma unroll
    for (int j = 1; j < 9; ++j) mx = fmaxf(mx, s[j]);
    float pr[9]; float l = 0.f;
    #pragma unroll
    for (int j = 0; j < 9; ++j) { pr[j] = __expf(s[j] - mx); l += pr[j]; }
    const float inv = 1.0f / l;

    float o[16];
    #pragma unroll
    for (int i = 0; i < 16; ++i) o[i] = 0.f;
    #pragma unroll
    for (int j = 0; j < 9; ++j) {
        const float pj = pr[j] * inv;
        const float* vr = &Vs[qi + j][d0];
        #pragma unroll
        for (int i = 0; i < 16; i += 4) {
            const float4 v4 = *reinterpret_cast<const float4*>(vr + i);
            o[i]     = fmaf(pj, v4.x, o[i]);
            o[i + 1] = fmaf(pj, v4.y, o[i + 1]);
            o[i + 2] = fmaf(pj, v4.z, o[i + 2]);
            o[i + 3] = fmaf(pj, v4.w, o[i + 3]);
        }
    }
    const int col0 = h * DHH + d0;
    unsigned short* op = ctx + (size_t)(b * SS + gq) * 1024
                       + (size_t)(col0 >> 5) * 64 + (col0 & 31);
    us8 h0, h1, l0, l1;
    #pragma unroll
    for (int i = 0; i < 8; ++i) {
        h0[i] = f2bf(o[i]);      l0[i] = f2bf(o[i]     - bf2f(h0[i]));
        h1[i] = f2bf(o[8 + i]);  l1[i] = f2bf(o[8 + i] - bf2f(h1[i]));
    }
    *reinterpret_cast<us8*>(op)      = h0;
    *reinterpret_cast<us8*>(op + 8)  = h1;
    *reinterpret_cast<us8*>(op + 32) = l0;
    *reinterpret_cast<us8*>(op + 40) = l1;
}

// ---------------------------------------------------------------- launch
extern "C" void kernel_launch(void* const* d_in, const int* in_sizes, int n_in,
                              void* d_out, int out_size, void* d_ws, size_t ws_size,
                              hipStream_t stream)
{
    const float* x     = (const float*)d_in[0];
    const float* w_in  = (const float*)d_in[1];
    const float* b_in  = (const float*)d_in[2];
    const float* w_out = (const float*)d_in[3];
    const float* b_out = (const float*)d_in[4];
    const float* w_ff1 = (const float*)d_in[5];
    const float* b_ff1 = (const float*)d_in[6];
    const float* w_ff2 = (const float*)d_in[7];
    const float* b_ff2 = (const float*)d_in[8];
    const float* ln1_g = (const float*)d_in[9];
    const float* ln1_b = (const float*)d_in[10];
    const float* ln2_g = (const float*)d_in[11];
    const float* ln2_b = (const float*)d_in[12];
    float* out = (float*)d_out;

    // workspace layout (bytes):
    // [0,16M)    lnq   split [8192][512]    (LN out, reused for LN2)
    // [16M,32M)  x1    fp32  [8192][512]
    // [32M,48M)  ctxs  split [8192][512]    \ overlaid later by
    // [48M,96M)  qkv   fp32  [8192][1536]   / ffh split [8192][2048] (67MB)
    // [99.1M..]  weights split (wqs|wos|w1s contiguous, then w2s)
    char* ws = (char*)d_ws;
    unsigned short* lnq  = (unsigned short*)ws;
    float*          x1   = (float*)(ws + 16777216);
    unsigned short* ctxs = (unsigned short*)(ws + 2 * 16777216);
    float*          qkv  = (float*)(ws + 3 * 16777216);
    unsigned short* ffh  = (unsigned short*)(ws + 2 * 16777216);   // 67,108,864 B
    unsigned short* wqs  = (unsigned short*)(ws + 2 * 16777216 + 67108864);
    unsigned short* wos  = wqs + (size_t)1536 * 1024;
    unsigned short* w1s  = wos + (size_t)512 * 1024;
    unsigned short* w2s  = w1s + (size_t)2048 * 1024;

    // weight conversions: one launch for all four weights
    conv_all<<<1536, 256, 0, stream>>>(w_in, w_out, w_ff1, w_ff2, wqs, w2s);

    // 1. LN1 -> split
    ln_kernel<<<MM, 128, 0, stream>>>(x, ln1_g, ln1_b, lnq);

    // 2. QKV: [8192,512]x[1536,512]^T -> fp32 qkv   (BN=64: grid 1536, 3 blocks/CU)
    gemm_tile<64, 0><<<dim3(QKV_N / 64, MM / 128), 256, 0, stream>>>(
        lnq, wqs, b_in, nullptr, qkv, nullptr, QKV_N, 512);

    // 3. local attention -> split ctx
    attn_kernel<<<dim3(SS / 64, BB, HH), 256, 0, stream>>>(qkv, ctxs);

    // 4. out-proj + residual: x1 = x + ctx @ out_w^T + b   (BN=64: grid 512, 3 blocks/CU)
    gemm_tile<64, 1><<<dim3(DD / 64, MM / 128), 256, 0, stream>>>(
        ctxs, wos, b_out, x, x1, nullptr, DD, 512);

    // 5. LN2 -> split
    ln_kernel<<<MM, 128, 0, stream>>>(x1, ln2_g, ln2_b, lnq);

    // 6. FF1 + GELU -> split ffh   (BN=64: grid 2048, 3 blocks/CU)
    gemm_tile<64, 2><<<dim3(DFF / 64, MM / 128), 256, 0, stream>>>(
        lnq, w1s, b_ff1, nullptr, nullptr, ffh, DFF, 512);

    // 7. FF2 + residual: out = x1 + ffh @ ff_w2^T + b   (BN=64: grid 512, K=2048)
    gemm_tile<64, 1><<<dim3(DD / 64, MM / 128), 256, 0, stream>>>(
        ffh, w2s, b_ff2, x1, out, nullptr, DD, 2048);
}